// Round 1
// baseline (492.409 us; speedup 1.0000x reference)
//
#include <hip/hip_runtime.h>

// Grouped node-mean pooling: in [B=32, T=512, N=21, C=256] f32 -> out [B,T,M=10,C] f32
// NODE_MAP = [[1,2],[3,4],[5,6],[7,8],[0,9],[10,11,12],[13,14],[15,16],[17,18],[19,20]]

#define N_NODES 21
#define M_GROUPS 10
#define C_CH 256
#define C4 (C_CH / 4)              // 64 float4 per (b,t,n) row

__device__ __constant__ int   g_n0[M_GROUPS]    = { 1, 3, 5, 7, 0, 10, 13, 15, 17, 19};
__device__ __constant__ int   g_n1[M_GROUPS]    = { 2, 4, 6, 8, 9, 11, 14, 16, 18, 20};
__device__ __constant__ int   g_n2[M_GROUPS]    = {-1,-1,-1,-1,-1, 12, -1, -1, -1, -1};
__device__ __constant__ float g_scale[M_GROUPS] = {0.5f, 0.5f, 0.5f, 0.5f, 0.5f,
                                                   (1.0f/3.0f), 0.5f, 0.5f, 0.5f, 0.5f};

__global__ __launch_bounds__(256) void pool_kernel(const float4* __restrict__ in,
                                                   float4* __restrict__ out,
                                                   int total4) {
    int idx = blockIdx.x * blockDim.x + threadIdx.x;
    if (idx >= total4) return;

    // out float4 layout: idx = bt * (M_GROUPS*C4) + m * C4 + c4
    int c4 = idx & (C4 - 1);               // C4 = 64, power of two
    int t  = idx >> 6;                     // bt * 10 + m
    int m  = t % M_GROUPS;
    int bt = t / M_GROUPS;

    // input float4 base for this (b,t): bt * N_NODES * C4
    int base = bt * (N_NODES * C4) + c4;

    int n0 = g_n0[m];
    int n1 = g_n1[m];
    int n2 = g_n2[m];
    float s = g_scale[m];

    float4 a = in[base + n0 * C4];
    float4 b = in[base + n1 * C4];

    float4 r;
    r.x = a.x + b.x;
    r.y = a.y + b.y;
    r.z = a.z + b.z;
    r.w = a.w + b.w;

    if (n2 >= 0) {
        float4 c = in[base + n2 * C4];
        r.x += c.x; r.y += c.y; r.z += c.z; r.w += c.w;
    }

    r.x *= s; r.y *= s; r.z *= s; r.w *= s;
    out[idx] = r;
}

extern "C" void kernel_launch(void* const* d_in, const int* in_sizes, int n_in,
                              void* d_out, int out_size, void* d_ws, size_t ws_size,
                              hipStream_t stream) {
    const float4* in  = (const float4*)d_in[0];
    float4*       out = (float4*)d_out;

    int total4 = out_size / 4;             // 32*512*10*256/4 = 10,485,760
    int block  = 256;
    int grid   = (total4 + block - 1) / block;

    pool_kernel<<<grid, block, 0, stream>>>(in, out, total4);
}